// Round 14
// baseline (331.227 us; speedup 1.0000x reference)
//
#include <hip/hip_runtime.h>
#include <hip/hip_bf16.h>
#include <cstdint>
#include <cstddef>

// ---------------- common types/helpers ----------------
typedef __attribute__((ext_vector_type(8))) short bf16x8;
typedef __attribute__((ext_vector_type(4))) float f32x4;
typedef __attribute__((ext_vector_type(16))) float f32x16;
typedef __attribute__((ext_vector_type(4))) unsigned int u32x4;

__device__ __forceinline__ unsigned short f2bf(float f) {
  __hip_bfloat16 h = __float2bfloat16(f);
  return *reinterpret_cast<unsigned short*>(&h);
}
__device__ __forceinline__ float bf2f(unsigned short u) {
  __hip_bfloat16 h = *reinterpret_cast<__hip_bfloat16*>(&u);
  return __bfloat162float(h);
}

typedef const __attribute__((address_space(1))) void gas_void;
typedef __attribute__((address_space(3))) void las_void;
__device__ __forceinline__ void gload_lds16(const void* g, void* l) {
  __builtin_amdgcn_global_load_lds((gas_void*)g, (las_void*)l, 16, 0, 0);
}

template <int N>
__device__ __forceinline__ void waitcnt_vm() {
  asm volatile("s_waitcnt vmcnt(%0)" :: "i"(N) : "memory");
}

// ---------------- problem constants ----------------
#define S_LEN 2048
#define HID 4096
#define NH 32
#define NKV 8
#define HD 128
#define NQKV 6144
static const float ATT_SCALE = 0.08838834764831845f; // 128^-0.5

// 32k-granular tiled layouts (k-chunk-major):
//  A-tiled32 (hid_bf, ctx): el (s,k) -> 16B-chunk
//    ((s>>7)*128 + (k>>5))*4*128 + ((k>>3)&3)*128 + (s&127); el byte (k&7)*2
//  B-tiled32 (Wcat BN=384, WoT BN=256): el (n,k) -> chunk
//    ((n/BN)*128 + (k>>5))*4*BN + ((k>>3)&3)*BN + (n%BN); el byte (k&7)*2
// Staging = linear copy; 32x32 fragment read = 32 lanes x consecutive 16B
// -> zero bank conflicts (verified R13).
// K global layout (attn): [kvh][kvt(32)][16KB tile], (krow=s&63, d) at byte
//   (((krow<<8) + ((d>>3)<<4)) ^ ((krow&7)<<4)) + ((d&7)<<1)
// V global layout (attn): (vrow=d, sl=s&63) at byte
//   (((vrow<<7) + ((sl>>3)<<4)) ^ ((vrow&7)<<4)) + ((sl&7)<<1)

// ---------------- fused prep: cvt+retile(hidden) + retile 4 weights ----------
__global__ void prep_kernel(const float* __restrict__ hidden, short* __restrict__ hid_bf,
                            const float* __restrict__ Wq, const float* __restrict__ Wk,
                            const float* __restrict__ Wv, const float* __restrict__ Wo,
                            short* __restrict__ Wcat, short* __restrict__ WoT) {
  __shared__ float tile[64][33];
  const int bid = blockIdx.x;
  const int t = threadIdx.x;

  if (bid >= 20480) {
    // hidden -> hid_bf tiled32. Block = 64k x 32s tile.
    const int hbid = bid - 20480;
    const int kb = (hbid & 63) * 64, sb = (hbid >> 6) * 32;
    {
      int sr = t >> 3, k4 = (t & 7) * 4;
#pragma unroll
      for (int i = 0; i < 2; ++i) {
        f32x4 v = *(const f32x4*)(hidden + (size_t)(sb + sr) * HID + kb + i * 32 + k4);
#pragma unroll
        for (int jj = 0; jj < 4; ++jj) tile[i * 32 + k4 + jj][sr] = v[jj];
      }
    }
    __syncthreads();
    const int ts = t & 31, c = t >> 5;     // c in 0..7, covers k = kb + c*8
    const int s = sb + ts;
    unsigned short o[8];
#pragma unroll
    for (int i = 0; i < 8; ++i) o[i] = f2bf(tile[c * 8 + i][ts]);
    size_t off16 = (((size_t)(s >> 7) * 128 + (kb >> 5) + (c >> 2)) * 4 + (c & 3)) * 128 + (s & 127);
    *(u32x4*)(hid_bf + off16 * 8) = *(const u32x4*)o;
    return;
  }

  const float* src; short* dst; int N, loc, noff, BNp;
  if (bid < 8192)       { src = Wq; dst = Wcat; N = 4096; loc = bid;         noff = 0;    BNp = 384; }
  else if (bid < 10240) { src = Wk; dst = Wcat; N = 1024; loc = bid - 8192;  noff = 4096; BNp = 384; }
  else if (bid < 12288) { src = Wv; dst = Wcat; N = 1024; loc = bid - 10240; noff = 5120; BNp = 384; }
  else                  { src = Wo; dst = WoT;  N = 4096; loc = bid - 12288; noff = 0;    BNp = 256; }
  const int kb = (loc & 63) * 64, nb = (loc >> 6) * 32;
  {
    int kr = t >> 3, c4 = (t & 7) * 4;
#pragma unroll
    for (int i = 0; i < 2; ++i) {
      int k = kr + i * 32;
      f32x4 v = *(const f32x4*)(src + (size_t)(kb + k) * N + nb + c4);
      tile[k][c4] = v[0]; tile[k][c4 + 1] = v[1];
      tile[k][c4 + 2] = v[2]; tile[k][c4 + 3] = v[3];
    }
  }
  __syncthreads();
  const int tn = t & 31, c = t >> 5;
  const int n = noff + nb + tn;
  const int nblk = n / BNp, nrow = n % BNp;
  unsigned short o[8];
#pragma unroll
  for (int i = 0; i < 8; ++i) o[i] = f2bf(tile[c * 8 + i][tn]);
  size_t off16 = (((size_t)nblk * 128 + (kb >> 5) + (c >> 2)) * 4 + (c & 3)) * BNp + nrow;
  *(u32x4*)(dst + off16 * 8) = *(const u32x4*)o;
}

// ---------------- depth-3 ring 32x32-MFMA GEMM on tiled operands ------------
// R14: BK=32, 4-buffer LDS ring, counted vmcnt leaving 2 tiles in flight.
// Per tile kt: vmcnt(2*LPT) -> barrier -> sched_barrier -> stage(kt+3) ->
// {reads, MFMA} x2 k-steps (no further barriers). WAR-safe: buf[(kt+3)&3]
// last read at kt-1, complete before barrier kt.
template <int MODE, int BN>
__global__ __launch_bounds__(512, 2) void gemm32r_kernel(
    const short* __restrict__ A, const short* __restrict__ Bt,
    int N, int K,
    float* __restrict__ Cf, short* __restrict__ qb_,
    short* __restrict__ kb_, short* __restrict__ vb_) {
  constexpr int BM = 128, WM = 2, WN = 4;
  constexpr int MT = BM / (WM * 32);       // 2
  constexpr int NTL = BN / (WN * 32);      // 3 (QKV) / 2 (O)
  constexpr int ASZ = 4 * BM * 8;          // shorts per A k-tile (4096)
  constexpr int BSZ = 4 * BN * 8;          // shorts per B k-tile
  constexpr int LA = ASZ / (512 * 8);      // 1
  constexpr int LB = BSZ / (512 * 8);      // 3 / 2
  constexpr int LPT = LA + LB;             // 4 / 3
  constexpr int BUF = ASZ + BSZ;

  __shared__ short lds[4 * BUF];

  const int tid = threadIdx.x, wid = tid >> 6, lane = tid & 63;
  const int wr = wid / WN, wc = wid % WN;
  const int l31 = lane & 31, lh = lane >> 5;
  const int brow = blockIdx.y * BM, bcol = blockIdx.x * BN;
  const int T = K >> 5;                    // 128 k-tiles

  f32x16 acc[MT][NTL] = {};

  auto stage = [&](int kt) {
    short* dstA = lds + (kt & 3) * BUF;
    const short* srcA = A + (size_t)(blockIdx.y * 128 + kt) * ASZ;
#pragma unroll
    for (int i = 0; i < LA; ++i) {
      int slot = i * 512 + tid;
      gload_lds16(srcA + slot * 8, dstA + slot * 8);
    }
    short* dstB = dstA + ASZ;
    const short* srcB = Bt + (size_t)(blockIdx.x * 128 + kt) * BSZ;
#pragma unroll
    for (int i = 0; i < LB; ++i) {
      int slot = i * 512 + tid;
      gload_lds16(srcB + slot * 8, dstB + slot * 8);
    }
  };

  stage(0); stage(1); stage(2);

  for (int kt = 0; kt < T; ++kt) {
    if (kt < T - 2)       waitcnt_vm<2 * LPT>();   // leave kt+1, kt+2 in flight
    else if (kt == T - 2) waitcnt_vm<LPT>();
    else                  waitcnt_vm<0>();
    __builtin_amdgcn_s_barrier();
    __builtin_amdgcn_sched_barrier(0);
    if (kt + 3 < T) stage(kt + 3);

    const short* As_ = lds + (kt & 3) * BUF;
    const short* Bs_ = As_ + ASZ;
#pragma unroll
    for (int st = 0; st < 2; ++st) {
      bf16x8 af[MT], bf[NTL];
      const int c = st * 2 + lh;             // k-chunk 0..3
#pragma unroll
      for (int mt = 0; mt < MT; ++mt)
        af[mt] = *(const bf16x8*)(As_ + (c * BM + wr * 64 + mt * 32 + l31) * 8);
#pragma unroll
      for (int nt = 0; nt < NTL; ++nt)
        bf[nt] = *(const bf16x8*)(Bs_ + (c * BN + wc * (BN / WN) + nt * 32 + l31) * 8);
      __builtin_amdgcn_s_setprio(1);
#pragma unroll
      for (int mt = 0; mt < MT; ++mt)
#pragma unroll
        for (int nt = 0; nt < NTL; ++nt)
          acc[mt][nt] = __builtin_amdgcn_mfma_f32_32x32x16_bf16(
              af[mt], bf[nt], acc[mt][nt], 0, 0, 0);
      __builtin_amdgcn_s_setprio(0);
    }
  }

  if (MODE == 0) {
#pragma unroll
    for (int mt = 0; mt < MT; ++mt)
#pragma unroll
      for (int nt = 0; nt < NTL; ++nt)
#pragma unroll
        for (int reg = 0; reg < 16; ++reg) {
          int row = brow + wr * 64 + mt * 32 + (reg & 3) + 8 * (reg >> 2) + 4 * lh;
          int col = bcol + wc * (BN / WN) + nt * 32 + l31;
          Cf[(size_t)row * N + col] = acc[mt][nt][reg];
        }
  } else {
#pragma unroll
    for (int nt = 0; nt < NTL; ++nt) {
      const int cb = bcol + wc * (BN / WN) + nt * 32;   // wave-uniform, 32-span
      const int d = (cb & 127) + l31;
      if (cb < 4096) {
        unsigned short* dst = (unsigned short*)qb_ + (size_t)(cb >> 7) * S_LEN * HD;
#pragma unroll
        for (int mt = 0; mt < MT; ++mt)
#pragma unroll
          for (int reg = 0; reg < 16; ++reg) {
            int row = brow + wr * 64 + mt * 32 + (reg & 3) + 8 * (reg >> 2) + 4 * lh;
            dst[(size_t)row * HD + d] = f2bf(acc[mt][nt][reg]);
          }
      } else if (cb < 5120) {
        char* base = (char*)kb_ + ((size_t)((cb - 4096) >> 7) << 19);
#pragma unroll
        for (int mt = 0; mt < MT; ++mt)
#pragma unroll
          for (int reg = 0; reg < 16; ++reg) {
            int row = brow + wr * 64 + mt * 32 + (reg & 3) + 8 * (reg >> 2) + 4 * lh;
            int krow = row & 63;
            size_t off = ((size_t)(row >> 6) << 14) +
                         ((((krow << 8) + ((d >> 3) << 4)) ^ ((krow & 7) << 4)) + ((d & 7) << 1));
            *(unsigned short*)(base + off) = f2bf(acc[mt][nt][reg]);
          }
      } else {
        char* base = (char*)vb_ + ((size_t)((cb - 5120) >> 7) << 19);
#pragma unroll
        for (int mt = 0; mt < MT; ++mt)
#pragma unroll
          for (int reg = 0; reg < 16; ++reg) {
            int row = brow + wr * 64 + mt * 32 + (reg & 3) + 8 * (reg >> 2) + 4 * lh;
            int sl = row & 63;
            size_t off = ((size_t)(row >> 6) << 14) +
                         ((((d << 7) + ((sl >> 3) << 4)) ^ ((d & 7) << 4)) + ((sl & 7) << 1));
            *(unsigned short*)(base + off) = f2bf(acc[mt][nt][reg]);
          }
      }
    }
  }
}

// ---------------- kernel: RoPE in place; Q row-major, K swizzled-tiled -------
__global__ void rope_kernel(short* __restrict__ qbuf, short* __restrict__ kbuf,
                            const float* __restrict__ cosT, const float* __restrict__ sinT) {
  int idx = blockIdx.x * 256 + threadIdx.x;
  const int total = (NH + NKV) * S_LEN * 64;
  if (idx >= total) return;
  int d = idx & 63;
  int rowi = idx >> 6;
  int s;
  unsigned short *p1, *p2;
  if (rowi < NH * S_LEN) {
    unsigned short* base = (unsigned short*)qbuf + (size_t)rowi * HD;
    s = rowi & (S_LEN - 1);
    p1 = base + d; p2 = base + d + 64;
  } else {
    int kr = rowi - NH * S_LEN;
    int kvh = kr >> 11; s = kr & (S_LEN - 1);
    char* base = (char*)kbuf + ((size_t)kvh << 19) + ((size_t)(s >> 6) << 14);
    int krow = s & 63, swz = (krow & 7) << 4;
    int dd = d + 64;
    p1 = (unsigned short*)(base + ((((krow << 8) + ((d >> 3) << 4)) ^ swz) + ((d & 7) << 1)));
    p2 = (unsigned short*)(base + ((((krow << 8) + ((dd >> 3) << 4)) ^ swz) + ((dd & 7) << 1)));
  }
  float x1 = bf2f(*p1);
  float x2 = bf2f(*p2);
  float c1 = cosT[s * HD + d], s1 = sinT[s * HD + d];
  *p1 = f2bf(x1 * c1 - x2 * s1);
  *p2 = f2bf(x2 * c1 + x1 * s1);
}

// ---------------- kernel: flash attention (causal, GQA 4:1) ----------------
// ctx written in A-tiled32 layout for the O-projection.
__global__ __launch_bounds__(512, 2) void attn_kernel(const short* __restrict__ qb_,
                                                      const short* __restrict__ kb_,
                                                      const short* __restrict__ vb_,
                                                      short* __restrict__ ctx) {
  const int bid = blockIdx.x;
  const int kvh = bid & 7;
  const int idx = bid >> 3;
  const int h = kvh * 4 + (idx & 3);
  const int slot = idx >> 2;
  const int tid = threadIdx.x, wid = tid >> 6, lane = tid & 63;
  const int r = lane & 15, g = lane >> 4;

  __shared__ short Ks[2][64 * 128];
  __shared__ short Vts[2][128 * 64];
  __shared__ short Ps[8][16 * 64];

  const int qb2s[2] = { slot, 15 - slot };
  const int nt0 = 2 * qb2s[0] + 2;
  const int T = 34;

  const char* kvbase_k = (const char*)kb_ + ((size_t)kvh << 19);
  const char* kvbase_v = (const char*)vb_ + ((size_t)kvh << 19);

  auto stage = [&](int tg, int b) {
    int kvt = (tg < nt0) ? tg : (tg - nt0);
    const char* kt = kvbase_k + ((size_t)kvt << 14);
    const char* vt = kvbase_v + ((size_t)kvt << 14);
#pragma unroll
    for (int i = 0; i < 2; ++i) {
      int ch = i * 8 + wid;
      gload_lds16(kt + ch * 1024 + lane * 16, (char*)&Ks[b][0] + ch * 1024);
      gload_lds16(vt + ch * 1024 + lane * 16, (char*)&Vts[b][0] + ch * 1024);
    }
  };

  stage(0, 0);
  int cur = 0, tglob = 0;

  for (int sec = 0; sec < 2; ++sec) {
    const int qb2 = qb2s[sec];
    const int nt = 2 * qb2 + 2;
    const int rowbase = qb2 * 128 + wid * 16;

    const unsigned short* qptr =
        (const unsigned short*)qb_ + ((size_t)h * S_LEN + rowbase) * HD;
    bf16x8 qf[4];
#pragma unroll
    for (int s4 = 0; s4 < 4; ++s4)
      qf[s4] = *(const bf16x8*)(qptr + (size_t)r * HD + s4 * 32 + g * 8);

    f32x4 oacc[8] = {};
    float m_run[4], l_run[4];
#pragma unroll
    for (int j = 0; j < 4; ++j) { m_run[j] = -1e30f; l_run[j] = 0.f; }

    for (int kvt = 0; kvt < nt; ++kvt, ++tglob) {
      __syncthreads();
      if (tglob + 1 < T) stage(tglob + 1, cur ^ 1);

      const char* Kc = (const char*)&Ks[cur][0];
      const char* Vc = (const char*)&Vts[cur][0];

      f32x4 sv[4] = {};
      __builtin_amdgcn_s_setprio(1);
#pragma unroll
      for (int n = 0; n < 4; ++n) {
        int krow = n * 16 + r;
        int swz = (krow & 7) << 4;
#pragma unroll
        for (int s4 = 0; s4 < 4; ++s4) {
          bf16x8 kf = *(const bf16x8*)(Kc + ((krow * 256 + s4 * 64 + g * 16) ^ swz));
          sv[n] = __builtin_amdgcn_mfma_f32_16x16x32_bf16(qf[s4], kf, sv[n], 0, 0, 0);
        }
      }
      __builtin_amdgcn_s_setprio(0);

      if (kvt * 64 + 63 > rowbase) {
#pragma unroll
        for (int n = 0; n < 4; ++n)
#pragma unroll
          for (int j = 0; j < 4; ++j) {
            int colg = kvt * 64 + n * 16 + r;
            int rowg = rowbase + g * 4 + j;
            sv[n][j] = (colg <= rowg) ? sv[n][j] * ATT_SCALE : -1e30f;
          }
      } else {
#pragma unroll
        for (int n = 0; n < 4; ++n)
#pragma unroll
          for (int j = 0; j < 4; ++j) sv[n][j] *= ATT_SCALE;
      }

      float pmax[4];
#pragma unroll
      for (int j = 0; j < 4; ++j)
        pmax[j] = fmaxf(fmaxf(sv[0][j], sv[1][j]), fmaxf(sv[2][j], sv[3][j]));
#pragma unroll
      for (int msk = 1; msk <= 8; msk <<= 1)
#pragma unroll
        for (int j = 0; j < 4; ++j) pmax[j] = fmaxf(pmax[j], __shfl_xor(pmax[j], msk));

      float sf[4], rsum[4];
#pragma unroll
      for (int j = 0; j < 4; ++j) {
        float mn = fmaxf(m_run[j], pmax[j]);
        sf[j] = __expf(m_run[j] - mn);
        m_run[j] = mn;
        rsum[j] = 0.f;
      }
#pragma unroll
      for (int n = 0; n < 4; ++n)
#pragma unroll
        for (int j = 0; j < 4; ++j) {
          float p = __expf(sv[n][j] - m_run[j]);
          sv[n][j] = p;
          rsum[j] += p;
        }
#pragma unroll
      for (int msk = 1; msk <= 8; msk <<= 1)
#pragma unroll
        for (int j = 0; j < 4; ++j) rsum[j] += __shfl_xor(rsum[j], msk);
#pragma unroll
      for (int j = 0; j < 4; ++j) l_run[j] = l_run[j] * sf[j] + rsum[j];
#pragma unroll
      for (int t = 0; t < 8; ++t)
#pragma unroll
        for (int j = 0; j < 4; ++j) oacc[t][j] *= sf[j];

#pragma unroll
      for (int n = 0; n < 4; ++n)
#pragma unroll
        for (int j = 0; j < 4; ++j) {
          int prow = g * 4 + j, pcol = n * 16 + r;
          int poff = (prow * 128 + pcol * 2) ^ ((prow & 7) << 4);
          *(unsigned short*)((char*)&Ps[wid][0] + poff) = f2bf(sv[n][j]);
        }

      __builtin_amdgcn_s_setprio(1);
#pragma unroll
      for (int s4 = 0; s4 < 2; ++s4) {
        bf16x8 pf = *(const bf16x8*)((const char*)&Ps[wid][0] +
                                     ((r * 128 + s4 * 64 + g * 16) ^ ((r & 7) << 4)));
#pragma unroll
        for (int t = 0; t < 8; ++t) {
          int vrow = t * 16 + r;
          bf16x8 vf = *(const bf16x8*)(Vc + ((vrow * 128 + s4 * 64 + g * 16) ^ ((vrow & 7) << 4)));
          oacc[t] = __builtin_amdgcn_mfma_f32_16x16x32_bf16(pf, vf, oacc[t], 0, 0, 0);
        }
      }
      __builtin_amdgcn_s_setprio(0);
      cur ^= 1;
    }

    // ---- epilogue: ctx in A-tiled32 layout ----
    float inv[4];
#pragma unroll
    for (int j = 0; j < 4; ++j) inv[j] = 1.0f / l_run[j];
#pragma unroll
    for (int t = 0; t < 8; ++t)
#pragma unroll
      for (int j = 0; j < 4; ++j) {
        int s = rowbase + g * 4 + j;
        int colg = h * HD + t * 16 + r;
        size_t off16 = (((size_t)(s >> 7) * 128 + (colg >> 5)) * 4 + ((colg >> 3) & 3)) * 128 + (s & 127);
        *(unsigned short*)((char*)ctx + off16 * 16 + (colg & 7) * 2) = f2bf(oacc[t][j] * inv[j]);
      }
  }
}

// ---------------- launcher ----------------
extern "C" void kernel_launch(void* const* d_in, const int* in_sizes, int n_in,
                              void* d_out, int out_size, void* d_ws, size_t ws_size,
                              hipStream_t stream) {
  const float* hidden = (const float*)d_in[0];
  const float* cosT   = (const float*)d_in[1];
  const float* sinT   = (const float*)d_in[2];
  const float* Wq = (const float*)d_in[4];
  const float* Wk = (const float*)d_in[5];
  const float* Wv = (const float*)d_in[6];
  const float* Wo = (const float*)d_in[7];
  float* out = (float*)d_out;

  char* ws = (char*)d_ws;
  short* hid_bf = (short*)(ws);                        // 16 MB  A-tiled32
  short* Wcat   = (short*)(ws + 16777216);             // 48 MB  B-tiled32 BN=384
  short* WoT    = (short*)(ws + 67108864);             // 32 MB  B-tiled32 BN=256
  short* qbuf   = (short*)(ws + 100663296);            // 16 MB  [32][2048][128]
  short* kbuf   = (short*)(ws + 117440512);            // 4 MB   swizzled tiles
  short* vbuf   = (short*)(ws + 121634816);            // 4 MB   swizzled tiles
  short* ctx    = (short*)(ws + 125829120);            // 16 MB  A-tiled32

  // fused prep: hidden cvt+retile + all 4 weight retiles, one dispatch
  prep_kernel<<<24576, 256, 0, stream>>>(hidden, hid_bf, Wq, Wk, Wv, Wo, Wcat, WoT);

  // QKV projection: 128x384, depth-3 ring, grid 16x16 = 1/CU
  gemm32r_kernel<1, 384><<<dim3(16, 16), 512, 0, stream>>>(
      hid_bf, Wcat, NQKV, HID, nullptr, qbuf, kbuf, vbuf);

  rope_kernel<<<20480, 256, 0, stream>>>(qbuf, kbuf, cosT, sinT);

  attn_kernel<<<256, 512, 0, stream>>>(qbuf, kbuf, vbuf, ctx);

  // O projection: 128x256, depth-3 ring, grid 16x16 = 1/CU
  gemm32r_kernel<0, 256><<<dim3(16, 16), 512, 0, stream>>>(
      ctx, WoT, HID, HID, out, nullptr, nullptr, nullptr);
}

// Round 15
// 321.600 us; speedup vs baseline: 1.0299x; 1.0299x over previous
//
#include <hip/hip_runtime.h>
#include <hip/hip_bf16.h>
#include <cstdint>
#include <cstddef>

// ---------------- common types/helpers ----------------
typedef __attribute__((ext_vector_type(8))) short bf16x8;
typedef __attribute__((ext_vector_type(4))) float f32x4;
typedef __attribute__((ext_vector_type(4))) unsigned int u32x4;

__device__ __forceinline__ unsigned short f2bf(float f) {
  __hip_bfloat16 h = __float2bfloat16(f);
  return *reinterpret_cast<unsigned short*>(&h);
}
__device__ __forceinline__ float bf2f(unsigned short u) {
  __hip_bfloat16 h = *reinterpret_cast<__hip_bfloat16*>(&u);
  return __bfloat162float(h);
}

typedef const __attribute__((address_space(1))) void gas_void;
typedef __attribute__((address_space(3))) void las_void;
__device__ __forceinline__ void gload_lds16(const void* g, void* l) {
  __builtin_amdgcn_global_load_lds((gas_void*)g, (las_void*)l, 16, 0, 0);
}

template <int N>
__device__ __forceinline__ void waitcnt_vm() {
  asm volatile("s_waitcnt vmcnt(%0)" :: "i"(N) : "memory");
}

// ---------------- problem constants ----------------
#define S_LEN 2048
#define HID 4096
#define NH 32
#define NKV 8
#define HD 128
#define NQKV 6144
static const float ATT_SCALE = 0.08838834764831845f; // 128^-0.5

// K global layout: [kvh][kvt(32)][16KB tile], element (krow=s&63, d) at byte
//   (((krow<<8) + ((d>>3)<<4)) ^ ((krow&7)<<4)) + ((d&7)<<1)
// V global layout: [kvh][kvt(32)][16KB tile], element (vrow=d, sl=s&63) at byte
//   (((vrow<<7) + ((sl>>3)<<4)) ^ ((vrow&7)<<4)) + ((sl&7)<<1)

// ---------------- fused prep: cvt(hidden) + Wq/Wk/Wv transposes --------------
// (Wo retile moved into attn dispatch -> off the critical path.)
// Regions by blockIdx.x:
//   [0,8192)      Wq  [4096][4096] -> Wcat[0..4096)
//   [8192,10240)  Wk  [4096][1024] -> Wcat[4096..5120)
//   [10240,12288) Wv  [4096][1024] -> Wcat[5120..6144)
//   [12288,16384) cvt hidden fp32 -> bf16
__global__ void prep_kernel(const float* __restrict__ hidden, short* __restrict__ hid_bf,
                            const float* __restrict__ Wq, const float* __restrict__ Wk,
                            const float* __restrict__ Wv,
                            short* __restrict__ Wcat) {
  __shared__ float tile[64][33];
  const int bid = blockIdx.x;
  const int t = threadIdx.x;
  if (bid >= 12288) {
    int i = ((bid - 12288) * 256 + t) * 8;
    f32x4 a = *(const f32x4*)(hidden + i);
    f32x4 b = *(const f32x4*)(hidden + i + 4);
    unsigned short o[8];
#pragma unroll
    for (int k = 0; k < 4; ++k) { o[k] = f2bf(a[k]); o[4 + k] = f2bf(b[k]); }
    *(u32x4*)(hid_bf + i) = *(const u32x4*)o;
    return;
  }
  const float* src; short* dst; int N, loc;
  if (bid < 8192)       { src = Wq; dst = Wcat;                      N = 4096; loc = bid; }
  else if (bid < 10240) { src = Wk; dst = Wcat + (size_t)4096 * HID; N = 1024; loc = bid - 8192; }
  else                  { src = Wv; dst = Wcat + (size_t)5120 * HID; N = 1024; loc = bid - 10240; }
  const int kb = (loc & 63) * 64, nb = (loc >> 6) * 32;
  {
    int kr = t >> 3, c4 = (t & 7) * 4;
#pragma unroll
    for (int i = 0; i < 2; ++i) {
      int k = kr + i * 32;
      f32x4 v = *(const f32x4*)(src + (size_t)(kb + k) * N + nb + c4);
      tile[k][c4] = v[0]; tile[k][c4 + 1] = v[1];
      tile[k][c4 + 2] = v[2]; tile[k][c4 + 3] = v[3];
    }
  }
  __syncthreads();
  int n = t >> 3, k0 = (t & 7) * 8;
  unsigned short o[8];
#pragma unroll
  for (int i = 0; i < 8; ++i) o[i] = f2bf(tile[k0 + i][n]);
  *(u32x4*)(dst + (size_t)(nb + n) * HID + kb + k0) = *(const u32x4*)o;
}

// ---------------- minimal-sync pipelined bf16 GEMM  C = A * Bt^T -------------
// R11 schedule (best measured): ONE vmcnt(0) + ONE barrier per K-tile (BK=64);
// staging bunched after barrier; LDS swizzle chunk ^= (row&7) both sides.

#define READ_A(MHL) { \
    const short* As_ = lds + (kt & 1) * BUF; \
    _Pragma("unroll") for (int m = 0; m < MHALF; ++m) \
    _Pragma("unroll") for (int kk = 0; kk < 2; ++kk) { \
      int row = (MHL) * (BM / 2) + wr * MSTEP + m * 16 + r; \
      int c = kk * 4 + g; \
      af[m][kk] = *(const bf16x8*)(As_ + row * 64 + ((c ^ (row & 7)) * 8)); \
    } }
#define READ_B(NHL) { \
    const short* Bs_ = lds + (kt & 1) * BUF + BM * 64; \
    _Pragma("unroll") for (int n = 0; n < NHALF; ++n) \
    _Pragma("unroll") for (int kk = 0; kk < 2; ++kk) { \
      int row = (NHL) * (BN / 2) + wc * NSTEP + n * 16 + r; \
      int c = kk * 4 + g; \
      bf[n][kk] = *(const bf16x8*)(Bs_ + row * 64 + ((c ^ (row & 7)) * 8)); \
    } }
#define MFMA_QUAD(MHL, NHL) { \
    __builtin_amdgcn_s_setprio(1); \
    _Pragma("unroll") for (int m = 0; m < MHALF; ++m) \
    _Pragma("unroll") for (int n = 0; n < NHALF; ++n) \
    _Pragma("unroll") for (int kk = 0; kk < 2; ++kk) \
      acc[(MHL)*MHALF + m][(NHL)*NHALF + n] = __builtin_amdgcn_mfma_f32_16x16x32_bf16( \
          af[m][kk], bf[n][kk], acc[(MHL)*MHALF + m][(NHL)*NHALF + n], 0, 0, 0); \
    __builtin_amdgcn_s_setprio(0); }

template <int MODE, int BM, int BN, int WM, int WN>
__global__ __launch_bounds__(WM * WN * 64, 2) void gemm8p_kernel(
    const short* __restrict__ A, const short* __restrict__ Bt,
    int M, int N, int K,
    float* __restrict__ Cf, short* __restrict__ qb_,
    short* __restrict__ kb_, short* __restrict__ vb_) {
  constexpr int NT = WM * WN * 64;
  constexpr int M_FR = BM / (WM * 16);
  constexpr int N_FR = BN / (WN * 16);
  constexpr int MHALF = M_FR / 2;
  constexpr int NHALF = N_FR / 2;
  constexpr int MSTEP = BM / (2 * WM);
  constexpr int NSTEP = BN / (2 * WN);
  constexpr int LA = (BM / 2) * 8 / NT;
  constexpr int LB = (BN / 2) * 8 / NT;
  constexpr int BUF = (BM + BN) * 64;

  __shared__ short lds[2 * BUF];

  const int tid = threadIdx.x, wid = tid >> 6, lane = tid & 63;
  const int wr = wid / WN, wc = wid % WN;
  const int r = lane & 15, g = lane >> 4;
  const int brow = blockIdx.y * BM, bcol = blockIdx.x * BN;
  const int T = K >> 6;

  f32x4 acc[M_FR][N_FR] = {};
  bf16x8 af[MHALF][2], bf[NHALF][2];

  auto stage_rgn = [&](int kt, int rgn) {
    short* buf = lds + (kt & 1) * BUF;
    if (rgn == 0 || rgn == 3) {
      const int mh = (rgn == 3);
      short* dst = buf + mh * (BM / 2) * 64;
      const short* src = A + (size_t)(brow + mh * (BM / 2)) * K + kt * 64;
#pragma unroll
      for (int i = 0; i < LA; ++i) {
        int slot = i * NT + tid;
        int row = slot >> 3, c2 = slot & 7;
        gload_lds16(src + (size_t)row * K + ((c2 ^ (row & 7)) * 8), dst + slot * 8);
      }
    } else {
      const int nh = (rgn == 2);
      short* dst = buf + BM * 64 + nh * (BN / 2) * 64;
      const short* src = Bt + (size_t)(bcol + nh * (BN / 2)) * K + kt * 64;
#pragma unroll
      for (int i = 0; i < LB; ++i) {
        int slot = i * NT + tid;
        int row = slot >> 3, c2 = slot & 7;
        gload_lds16(src + (size_t)row * K + ((c2 ^ (row & 7)) * 8), dst + slot * 8);
      }
    }
  };

  stage_rgn(0, 0); stage_rgn(0, 1); stage_rgn(0, 2); stage_rgn(0, 3);

  for (int kt = 0; kt < T; ++kt) {
    const bool nl = (kt + 1 < T);
    waitcnt_vm<0>();
    __builtin_amdgcn_s_barrier();
    __builtin_amdgcn_sched_barrier(0);
    READ_A(0); READ_B(0);
    if (nl) { stage_rgn(kt + 1, 0); stage_rgn(kt + 1, 1);
              stage_rgn(kt + 1, 2); stage_rgn(kt + 1, 3); }
    asm volatile("s_waitcnt lgkmcnt(0)" ::: "memory");
    __builtin_amdgcn_sched_barrier(0);
    MFMA_QUAD(0, 0);
    READ_B(1);
    asm volatile("s_waitcnt lgkmcnt(0)" ::: "memory");
    __builtin_amdgcn_sched_barrier(0);
    MFMA_QUAD(0, 1);
    READ_A(1);
    asm volatile("s_waitcnt lgkmcnt(0)" ::: "memory");
    __builtin_amdgcn_sched_barrier(0);
    MFMA_QUAD(1, 1);
    READ_B(0);
    asm volatile("s_waitcnt lgkmcnt(0)" ::: "memory");
    __builtin_amdgcn_sched_barrier(0);
    MFMA_QUAD(1, 0);
  }

  if (MODE == 0) {
#pragma unroll
    for (int fm = 0; fm < M_FR; ++fm)
#pragma unroll
      for (int fn = 0; fn < N_FR; ++fn)
#pragma unroll
        for (int j = 0; j < 4; ++j) {
          int row = brow + (fm / MHALF) * (BM / 2) + wr * MSTEP + (fm % MHALF) * 16 + g * 4 + j;
          int col = bcol + (fn / NHALF) * (BN / 2) + wc * NSTEP + (fn % NHALF) * 16 + r;
          Cf[(size_t)row * N + col] = acc[fm][fn][j];
        }
  } else {
#pragma unroll
    for (int fn = 0; fn < N_FR; ++fn) {
      const int cb = bcol + (fn / NHALF) * (BN / 2) + wc * NSTEP + (fn % NHALF) * 16;
      if (cb < 4096) {
        unsigned short* dst = (unsigned short*)qb_ + (size_t)(cb >> 7) * S_LEN * HD;
        const int d0 = cb & 127;
#pragma unroll
        for (int fm = 0; fm < M_FR; ++fm)
#pragma unroll
          for (int j = 0; j < 4; ++j) {
            int row = brow + (fm / MHALF) * (BM / 2) + wr * MSTEP + (fm % MHALF) * 16 + g * 4 + j;
            dst[(size_t)row * HD + d0 + r] = f2bf(acc[fm][fn][j]);
          }
      } else if (cb < 5120) {
        char* base = (char*)kb_ + ((size_t)((cb - 4096) >> 7) << 19);
        const int d = cb & 127;
#pragma unroll
        for (int fm = 0; fm < M_FR; ++fm)
#pragma unroll
          for (int j = 0; j < 4; ++j) {
            int row = brow + (fm / MHALF) * (BM / 2) + wr * MSTEP + (fm % MHALF) * 16 + g * 4 + j;
            int dd = d + r;
            int krow = row & 63;
            size_t off = ((size_t)(row >> 6) << 14) +
                         ((((krow << 8) + ((dd >> 3) << 4)) ^ ((krow & 7) << 4)) + ((dd & 7) << 1));
            *(unsigned short*)(base + off) = f2bf(acc[fm][fn][j]);
          }
      } else {
        char* base = (char*)vb_ + ((size_t)((cb - 5120) >> 7) << 19);
        const int d = cb & 127;
#pragma unroll
        for (int fm = 0; fm < M_FR; ++fm)
#pragma unroll
          for (int j = 0; j < 4; ++j) {
            int row = brow + (fm / MHALF) * (BM / 2) + wr * MSTEP + (fm % MHALF) * 16 + g * 4 + j;
            int dd = d + r;
            int sl = row & 63;
            size_t off = ((size_t)(row >> 6) << 14) +
                         ((((dd << 7) + ((sl >> 3) << 4)) ^ ((dd & 7) << 4)) + ((sl & 7) << 1));
            *(unsigned short*)(base + off) = f2bf(acc[fm][fn][j]);
          }
      }
    }
  }
}

// ---------------- kernel: RoPE in place; Q row-major, K swizzled-tiled -------
__global__ void rope_kernel(short* __restrict__ qbuf, short* __restrict__ kbuf,
                            const float* __restrict__ cosT, const float* __restrict__ sinT) {
  int idx = blockIdx.x * 256 + threadIdx.x;
  const int total = (NH + NKV) * S_LEN * 64;
  if (idx >= total) return;
  int d = idx & 63;
  int rowi = idx >> 6;
  int s;
  unsigned short *p1, *p2;
  if (rowi < NH * S_LEN) {
    unsigned short* base = (unsigned short*)qbuf + (size_t)rowi * HD;
    s = rowi & (S_LEN - 1);
    p1 = base + d; p2 = base + d + 64;
  } else {
    int kr = rowi - NH * S_LEN;
    int kvh = kr >> 11; s = kr & (S_LEN - 1);
    char* base = (char*)kbuf + ((size_t)kvh << 19) + ((size_t)(s >> 6) << 14);
    int krow = s & 63, swz = (krow & 7) << 4;
    int dd = d + 64;
    p1 = (unsigned short*)(base + ((((krow << 8) + ((d >> 3) << 4)) ^ swz) + ((d & 7) << 1)));
    p2 = (unsigned short*)(base + ((((krow << 8) + ((dd >> 3) << 4)) ^ swz) + ((dd & 7) << 1)));
  }
  float x1 = bf2f(*p1);
  float x2 = bf2f(*p2);
  float c1 = cosT[s * HD + d], s1 = sinT[s * HD + d];
  *p1 = f2bf(x1 * c1 - x2 * s1);
  *p2 = f2bf(x2 * c1 + x1 * s1);
}

// ---------------- kernel: flash attention + fused Wo retile -----------------
// bid < 256: causal GQA flash attention (unchanged from R11).
// bid >= 256: retile 2 tiles of Wo [4096][4096] fp32 -> WoT bf16 B^T
//             (96 MB of BW work hidden under attention's compute).
__global__ __launch_bounds__(512, 2) void attn_kernel(const short* __restrict__ qb_,
                                                      const short* __restrict__ kb_,
                                                      const short* __restrict__ vb_,
                                                      short* __restrict__ ctx,
                                                      const float* __restrict__ Wo,
                                                      short* __restrict__ WoT) {
  const int bid = blockIdx.x;
  const int tid = threadIdx.x;

  __shared__ short Ks[2][64 * 128];
  __shared__ short Vts[2][128 * 64];
  __shared__ short Ps[8][16 * 64];

  if (bid >= 256) {
    // ---- Wo retile region: 2 tiles per block, scratch aliased into Ks ----
    float* tf = (float*)&Ks[0][0];            // 2 x 64x34 floats = 17.4KB < 32KB
    const int sub = tid >> 8, tt = tid & 255;
    float* tile = tf + sub * (64 * 34);
    const int loc = (bid - 256) * 2 + sub;    // 0..8191
    const int kb = (loc & 63) * 64, nb = (loc >> 6) * 32;
    {
      int kr = tt >> 3, c4 = (tt & 7) * 4;
#pragma unroll
      for (int i = 0; i < 2; ++i) {
        int k = kr + i * 32;
        f32x4 v = *(const f32x4*)(Wo + (size_t)(kb + k) * HID + nb + c4);
        tile[k * 34 + c4] = v[0]; tile[k * 34 + c4 + 1] = v[1];
        tile[k * 34 + c4 + 2] = v[2]; tile[k * 34 + c4 + 3] = v[3];
      }
    }
    __syncthreads();
    int n = tt >> 3, k0 = (tt & 7) * 8;
    unsigned short o[8];
#pragma unroll
    for (int i = 0; i < 8; ++i) o[i] = f2bf(tile[(k0 + i) * 34 + n]);
    *(u32x4*)(WoT + (size_t)(nb + n) * HID + kb + k0) = *(const u32x4*)o;
    return;
  }

  const int kvh = bid & 7;
  const int idx = bid >> 3;
  const int h = kvh * 4 + (idx & 3);
  const int slot = idx >> 2;
  const int wid = tid >> 6, lane = tid & 63;
  const int r = lane & 15, g = lane >> 4;

  const int qb2s[2] = { slot, 15 - slot };
  const int nt0 = 2 * qb2s[0] + 2;
  const int T = 34;

  const char* kvbase_k = (const char*)kb_ + ((size_t)kvh << 19);
  const char* kvbase_v = (const char*)vb_ + ((size_t)kvh << 19);

  auto stage = [&](int tg, int b) {
    int kvt = (tg < nt0) ? tg : (tg - nt0);
    const char* kt = kvbase_k + ((size_t)kvt << 14);
    const char* vt = kvbase_v + ((size_t)kvt << 14);
#pragma unroll
    for (int i = 0; i < 2; ++i) {
      int ch = i * 8 + wid;
      gload_lds16(kt + ch * 1024 + lane * 16, (char*)&Ks[b][0] + ch * 1024);
      gload_lds16(vt + ch * 1024 + lane * 16, (char*)&Vts[b][0] + ch * 1024);
    }
  };

  stage(0, 0);
  int cur = 0, tglob = 0;

  for (int sec = 0; sec < 2; ++sec) {
    const int qb2 = qb2s[sec];
    const int nt = 2 * qb2 + 2;
    const int rowbase = qb2 * 128 + wid * 16;

    const unsigned short* qptr =
        (const unsigned short*)qb_ + ((size_t)h * S_LEN + rowbase) * HD;
    bf16x8 qf[4];
#pragma unroll
    for (int s4 = 0; s4 < 4; ++s4)
      qf[s4] = *(const bf16x8*)(qptr + (size_t)r * HD + s4 * 32 + g * 8);

    f32x4 oacc[8] = {};
    float m_run[4], l_run[4];
#pragma unroll
    for (int j = 0; j < 4; ++j) { m_run[j] = -1e30f; l_run[j] = 0.f; }

    for (int kvt = 0; kvt < nt; ++kvt, ++tglob) {
      __syncthreads();
      if (tglob + 1 < T) stage(tglob + 1, cur ^ 1);

      const char* Kc = (const char*)&Ks[cur][0];
      const char* Vc = (const char*)&Vts[cur][0];

      f32x4 sv[4] = {};
      __builtin_amdgcn_s_setprio(1);
#pragma unroll
      for (int n = 0; n < 4; ++n) {
        int krow = n * 16 + r;
        int swz = (krow & 7) << 4;
#pragma unroll
        for (int s4 = 0; s4 < 4; ++s4) {
          bf16x8 kf = *(const bf16x8*)(Kc + ((krow * 256 + s4 * 64 + g * 16) ^ swz));
          sv[n] = __builtin_amdgcn_mfma_f32_16x16x32_bf16(qf[s4], kf, sv[n], 0, 0, 0);
        }
      }
      __builtin_amdgcn_s_setprio(0);

      if (kvt * 64 + 63 > rowbase) {
#pragma unroll
        for (int n = 0; n < 4; ++n)
#pragma unroll
          for (int j = 0; j < 4; ++j) {
            int colg = kvt * 64 + n * 16 + r;
            int rowg = rowbase + g * 4 + j;
            sv[n][j] = (colg <= rowg) ? sv[n][j] * ATT_SCALE : -1e30f;
          }
      } else {
#pragma unroll
        for (int n = 0; n < 4; ++n)
#pragma unroll
          for (int j = 0; j < 4; ++j) sv[n][j] *= ATT_SCALE;
      }

      float pmax[4];
#pragma unroll
      for (int j = 0; j < 4; ++j)
        pmax[j] = fmaxf(fmaxf(sv[0][j], sv[1][j]), fmaxf(sv[2][j], sv[3][j]));
#pragma unroll
      for (int msk = 1; msk <= 8; msk <<= 1)
#pragma unroll
        for (int j = 0; j < 4; ++j) pmax[j] = fmaxf(pmax[j], __shfl_xor(pmax[j], msk));

      float sf[4], rsum[4];
#pragma unroll
      for (int j = 0; j < 4; ++j) {
        float mn = fmaxf(m_run[j], pmax[j]);
        sf[j] = __expf(m_run[j] - mn);
        m_run[j] = mn;
        rsum[j] = 0.f;
      }
#pragma unroll
      for (int n = 0; n < 4; ++n)
#pragma unroll
        for (int j = 0; j < 4; ++j) {
          float p = __expf(sv[n][j] - m_run[j]);
          sv[n][j] = p;
          rsum[j] += p;
        }
#pragma unroll
      for (int msk = 1; msk <= 8; msk <<= 1)
#pragma unroll
        for (int j = 0; j < 4; ++j) rsum[j] += __shfl_xor(rsum[j], msk);
#pragma unroll
      for (int j = 0; j < 4; ++j) l_run[j] = l_run[j] * sf[j] + rsum[j];
#pragma unroll
      for (int t = 0; t < 8; ++t)
#pragma unroll
        for (int j = 0; j < 4; ++j) oacc[t][j] *= sf[j];

#pragma unroll
      for (int n = 0; n < 4; ++n)
#pragma unroll
        for (int j = 0; j < 4; ++j) {
          int prow = g * 4 + j, pcol = n * 16 + r;
          int poff = (prow * 128 + pcol * 2) ^ ((prow & 7) << 4);
          *(unsigned short*)((char*)&Ps[wid][0] + poff) = f2bf(sv[n][j]);
        }

      __builtin_amdgcn_s_setprio(1);
#pragma unroll
      for (int s4 = 0; s4 < 2; ++s4) {
        bf16x8 pf = *(const bf16x8*)((const char*)&Ps[wid][0] +
                                     ((r * 128 + s4 * 64 + g * 16) ^ ((r & 7) << 4)));
#pragma unroll
        for (int t = 0; t < 8; ++t) {
          int vrow = t * 16 + r;
          bf16x8 vf = *(const bf16x8*)(Vc + ((vrow * 128 + s4 * 64 + g * 16) ^ ((vrow & 7) << 4)));
          oacc[t] = __builtin_amdgcn_mfma_f32_16x16x32_bf16(pf, vf, oacc[t], 0, 0, 0);
        }
      }
      __builtin_amdgcn_s_setprio(0);
      cur ^= 1;
    }

    float inv[4];
#pragma unroll
    for (int j = 0; j < 4; ++j) inv[j] = 1.0f / l_run[j];
#pragma unroll
    for (int t = 0; t < 8; ++t)
#pragma unroll
      for (int j = 0; j < 4; ++j) {
        int rowg = rowbase + g * 4 + j;
        int colg = h * HD + t * 16 + r;
        ((unsigned short*)ctx)[(size_t)rowg * HID + colg] = f2bf(oacc[t][j] * inv[j]);
      }
  }
}

// ---------------- launcher ----------------
extern "C" void kernel_launch(void* const* d_in, const int* in_sizes, int n_in,
                              void* d_out, int out_size, void* d_ws, size_t ws_size,
                              hipStream_t stream) {
  const float* hidden = (const float*)d_in[0];
  const float* cosT   = (const float*)d_in[1];
  const float* sinT   = (const float*)d_in[2];
  const float* Wq = (const float*)d_in[4];
  const float* Wk = (const float*)d_in[5];
  const float* Wv = (const float*)d_in[6];
  const float* Wo = (const float*)d_in[7];
  float* out = (float*)d_out;

  char* ws = (char*)d_ws;
  short* hid_bf = (short*)(ws);                        // 16 MB
  short* Wcat   = (short*)(ws + 16777216);             // 48 MB  [6144][4096] bf16 (B^T)
  short* WoT    = (short*)(ws + 67108864);             // 32 MB  [4096][4096] bf16 (B^T)
  short* qbuf   = (short*)(ws + 100663296);            // 16 MB  [32][2048][128]
  short* kbuf   = (short*)(ws + 117440512);            // 4 MB   swizzled tiles
  short* vbuf   = (short*)(ws + 121634816);            // 4 MB   swizzled tiles
  short* ctx    = (short*)(ws + 125829120);            // 16 MB  [2048][4096]

  // prep: hidden cvt + Wq/Wk/Wv transposes (Wo moved into attn dispatch)
  prep_kernel<<<16384, 256, 0, stream>>>(hidden, hid_bf, Wq, Wk, Wv, Wcat);

  // QKV projection: 128x384 tile, grid (16,16) = 256 blocks = 1/CU
  gemm8p_kernel<1, 128, 384, 2, 4><<<dim3(16, 16), 512, 0, stream>>>(
      hid_bf, Wcat, S_LEN, NQKV, HID, nullptr, qbuf, kbuf, vbuf);

  rope_kernel<<<20480, 256, 0, stream>>>(qbuf, kbuf, cosT, sinT);

  // attention (256 blocks) + fused Wo retile (4096 blocks)
  attn_kernel<<<4352, 512, 0, stream>>>(qbuf, kbuf, vbuf, ctx, Wo, WoT);

  // O projection: 128x256 tile, grid (16,16) = 256 blocks = 1/CU
  gemm8p_kernel<0, 128, 256, 2, 4><<<dim3(16, 16), 512, 0, stream>>>(
      ctx, WoT, S_LEN, HID, HID, out, nullptr, nullptr, nullptr);
}